// Round 23
// baseline (631.571 us; speedup 1.0000x reference)
//
#include <hip/hip_runtime.h>
#include <math.h>

// Problem constants
constexpr int B_ = 64, N_ = 1024, M_ = 32, T_ = 8;
constexpr int OUT_ = 1000, NSO_ = 256;

#define DEVFN __device__ __forceinline__

typedef __attribute__((ext_vector_type(8))) short bf16x8;
typedef __attribute__((ext_vector_type(4))) float f32x4;

DEVFN float blockReduceSum(float v, float* buf) {
  int t = threadIdx.x;
  buf[t] = v; __syncthreads();
  for (int off = blockDim.x >> 1; off > 0; off >>= 1) {
    if (t < off) buf[t] += buf[t + off];
    __syncthreads();
  }
  float r = buf[0];
  __syncthreads();
  return r;
}

DEVFN float sigmoidf_(float x) { return 1.f / (1.f + __expf(-x)); }

DEVFN unsigned short f2bf(float f) {          // RNE float->bf16
  unsigned u = __float_as_uint(f);
  unsigned r = (u + 0x7FFFu + ((u >> 16) & 1u)) >> 16;
  return (unsigned short)r;
}
DEVFN float bf2f(unsigned short h) { return __uint_as_float((unsigned)h << 16); }

// ---- block reductions for wide blocks (NW waves), shuffle + small LDS ----
template<int NW>
DEVFN float bsum(float v, float* red) {
  #pragma unroll
  for (int o = 32; o > 0; o >>= 1) v += __shfl_xor(v, o);
  int w = threadIdx.x >> 6, ln = threadIdx.x & 63;
  if (ln == 0) red[w] = v;
  __syncthreads();
  if (w == 0) {
    float x = (ln < NW) ? red[ln] : 0.f;
    #pragma unroll
    for (int o = 8; o > 0; o >>= 1) x += __shfl_xor(x, o);
    if (ln == 0) red[0] = x;
  }
  __syncthreads();
  float r = red[0];
  __syncthreads();
  return r;
}

template<int NW>
DEVFN float bmax(float v, float* red) {
  #pragma unroll
  for (int o = 32; o > 0; o >>= 1) v = fmaxf(v, __shfl_xor(v, o));
  int w = threadIdx.x >> 6, ln = threadIdx.x & 63;
  if (ln == 0) red[w] = v;
  __syncthreads();
  if (w == 0) {
    float x = (ln < NW) ? red[ln] : -INFINITY;
    #pragma unroll
    for (int o = 8; o > 0; o >>= 1) x = fmaxf(x, __shfl_xor(x, o));
    if (ln == 0) red[0] = x;
  }
  __syncthreads();
  float r = red[0];
  __syncthreads();
  return r;
}

// ---- BN scale/shift from partial stats, computed per-block in LDS ----
DEVFN void bn_ssl(float2* ssl, const float* bnpart, const float* g, const float* bb,
                  int C, int ns, float inv_n) {
  for (int c = threadIdx.x; c < C; c += blockDim.x) {
    float s1 = 0.f, s2 = 0.f;
    for (int s = 0; s < ns; ++s) { s1 += bnpart[(c * ns + s) * 2]; s2 += bnpart[(c * ns + s) * 2 + 1]; }
    float m = s1 * inv_n;
    float var = s2 * inv_n - m * m;
    float rstd = rsqrtf(var + 1e-5f);
    float sc = g[c] * rstd;
    ssl[c] = make_float2(sc, bb[c] - m * sc);
  }
}

// ---------------- conv weight prep: wt2[10][32][16], wt3[9][64][32], wt4[9][64][64] bf16 ----------------
__global__ __launch_bounds__(256)
void k_wprep(const float* __restrict__ c2w, const float* __restrict__ c3w,
             const float* __restrict__ c4w, unsigned short* __restrict__ wt2,
             unsigned short* __restrict__ wt3, unsigned short* __restrict__ wt4) {
  int i = blockIdx.x * 256 + threadIdx.x;
  if (i < 5120) {               // wt2: tap(10) x co(32) x ci(16); tap 9 = zeros
    int tap = i / 512, co = (i / 16) % 32, ci = i & 15;
    wt2[i] = (tap < 9) ? f2bf(c2w[(co * 16 + ci) * 9 + tap]) : 0;
  } else if (i < 5120 + 18432) { // wt3: tap(9) x co(64) x ci(32)
    int j = i - 5120;
    int tap = j / 2048, co = (j / 32) % 64, ci = j & 31;
    wt3[j] = f2bf(c3w[(co * 32 + ci) * 9 + tap]);
  } else if (i < 5120 + 18432 + 36864) { // wt4: tap(9) x co(64) x ci(64)
    int j = i - 5120 - 18432;
    int tap = j / 4096, co = (j / 64) % 64, ci = j & 63;
    wt4[j] = f2bf(c4w[(co * 64 + ci) * 9 + tap]);
  }
}

// ---------------- nlm_w1 [n][32m][256c] fp32 -> [n][256c][32m] bf16 ----------------
__global__ __launch_bounds__(256)
void k_w1t(const float* __restrict__ w1, unsigned short* __restrict__ w1t) {
  int n = blockIdx.x;
  __shared__ float tile[32][260];
  const float* src = w1 + (size_t)n * 8192;
  for (int i = threadIdx.x; i < 8192; i += 256)
    tile[i >> 8][i & 255] = src[i];
  __syncthreads();
  int c = threadIdx.x;
  unsigned short* dst = w1t + ((size_t)n * 256 + c) * 32;
  #pragma unroll
  for (int q = 0; q < 8; ++q) {
    ushort4 o;
    o.x = f2bf(tile[q * 4 + 0][c]); o.y = f2bf(tile[q * 4 + 1][c]);
    o.z = f2bf(tile[q * 4 + 2][c]); o.w = f2bf(tile[q * 4 + 3][c]);
    *reinterpret_cast<ushort4*>(dst + q * 4) = o;
  }
}

// ---------------- synw[512+k][j] fp32 -> synw2t[j][k] bf16 (transpose) ----------------
__global__ __launch_bounds__(256)
void k_synwt(const float* __restrict__ synw2, unsigned short* __restrict__ Bt) {
  int j0 = blockIdx.x * 64, k0 = blockIdx.y * 64;
  __shared__ float tile[64][65];
  for (int i = threadIdx.x; i < 4096; i += 256) {
    int kk = i >> 6, jj = i & 63;
    tile[kk][jj] = synw2[(size_t)(k0 + kk) * 2048 + j0 + jj];
  }
  __syncthreads();
  int jj = threadIdx.x >> 2, kq = (threadIdx.x & 3) * 16;
  unsigned short* dst = Bt + (size_t)(j0 + jj) * 1024 + k0 + kq;
  #pragma unroll
  for (int q = 0; q < 4; ++q) {
    ushort4 o;
    o.x = f2bf(tile[kq + q * 4 + 0][jj]); o.y = f2bf(tile[kq + q * 4 + 1][jj]);
    o.z = f2bf(tile[kq + q * 4 + 2][jj]); o.w = f2bf(tile[kq + q * 4 + 3][jj]);
    *reinterpret_cast<ushort4*>(dst + q * 4) = o;
  }
}

// ---------------- conv1: VALU tiled conv (CIN=3), fp32 in, bf16 out ----------------
__global__ __launch_bounds__(256)
void k_conv1(const float* __restrict__ in, const float* __restrict__ wgl,
             unsigned short* __restrict__ outp) {
  constexpr int HW = 64, TY = 4, XV = 4, XQ = 16, CPT = 4;
  __shared__ __align__(16) float ins[3][TY + 2][HW + 8];
  const int b = blockIdx.x, y0 = blockIdx.y * TY, tid = threadIdx.x;
  const int sp = tid & 63;
  const int cg = __builtin_amdgcn_readfirstlane(tid >> 6);
  const int xq = sp % XQ, yr = sp / XQ, x0 = xq * XV;
  float acc[CPT][XV];
  #pragma unroll
  for (int j = 0; j < CPT; ++j)
    #pragma unroll
    for (int k = 0; k < XV; ++k) acc[j][k] = 0.f;
  constexpr int NEL = 3 * (TY + 2) * (HW + 8);
  for (int i = tid; i < NEL; i += 256) {
    int col = i % (HW + 8), row = (i / (HW + 8)) % (TY + 2), ci = i / ((HW + 8) * (TY + 2));
    int gx = col - 4, gy = y0 + row - 1;
    float v = 0.f;
    if (gx >= 0 && gx < HW && gy >= 0 && gy < HW)
      v = in[((size_t)(b * 3 + ci) * HW + gy) * HW + gx];
    ins[ci][row][col] = v;
  }
  __syncthreads();
  for (int ci = 0; ci < 3; ++ci) {
    const float* wci = wgl + ((size_t)(cg * CPT) * 3 + ci) * 9;
    #pragma unroll
    for (int dy = 0; dy < 3; ++dy) {
      const float* r = &ins[ci][yr + dy][x0 + 4];
      float win[6];
      win[0] = r[-1];
      float4 m = *reinterpret_cast<const float4*>(r);
      win[1] = m.x; win[2] = m.y; win[3] = m.z; win[4] = m.w;
      win[5] = r[4];
      #pragma unroll
      for (int j = 0; j < CPT; ++j) {
        const float* wj = wci + (size_t)j * 27 + dy * 3;
        float w0 = wj[0], w1 = wj[1], w2 = wj[2];
        #pragma unroll
        for (int k = 0; k < XV; ++k)
          acc[j][k] = fmaf(win[k], w0, fmaf(win[k + 1], w1, fmaf(win[k + 2], w2, acc[j][k])));
      }
    }
  }
  #pragma unroll
  for (int j = 0; j < CPT; ++j) {
    unsigned short* op = outp + (((size_t)b * 16 + cg * CPT + j) * HW + y0 + yr) * HW + x0;
    ushort4 o;
    o.x = f2bf(acc[j][0]); o.y = f2bf(acc[j][1]); o.z = f2bf(acc[j][2]); o.w = f2bf(acc[j][3]);
    *reinterpret_cast<ushort4*>(op) = o;
  }
}

// ---------------- conv2 via MFMA: CIN=16, COUT=32, HW=64; BN1+ReLU fused at staging ----------------
__global__ __launch_bounds__(256)
void k_conv2_mfma(const unsigned short* __restrict__ in, const unsigned short* __restrict__ wt2,
                  const float* __restrict__ bnpart, const float* __restrict__ bng,
                  const float* __restrict__ bnb, unsigned short* __restrict__ outp) {
  const int b = blockIdx.x, y = blockIdx.y;
  const int tid = threadIdx.x;
  const int w = tid >> 6, lane = tid & 63;
  const int col = lane & 15, kg = lane >> 4;
  const int p0 = w * 16;
  __shared__ unsigned short lds[3][68][16];
  __shared__ float2 ssl[16];
  bn_ssl(ssl, bnpart, bng, bnb, 16, 32, 1.f / (float)(B_ * 4096));
  __syncthreads();
  for (int i = tid; i < 3 * 66 * 16; i += 256) {
    int px = i % 66, row = (i / 66) % 3, ci = i / 198;
    int gy = y + row - 1, gx = px - 1;
    float v = 0.f;
    if (gy >= 0 && gy < 64 && gx >= 0 && gx < 64) {
      float2 s = ssl[ci];
      v = fmaxf(fmaf(bf2f(in[((size_t)(b * 16 + ci) * 64 + gy) * 64 + gx]), s.x, s.y), 0.f);
    }
    lds[row][px][ci] = f2bf(v);
  }
  __syncthreads();
  f32x4 acc0 = {0.f, 0.f, 0.f, 0.f}, acc1 = {0.f, 0.f, 0.f, 0.f};
  const int tsel = kg >> 1, ci0 = (kg & 1) * 8;
  #pragma unroll
  for (int p = 0; p < 5; ++p) {
    int tap = 2 * p + tsel;
    int dy = (tap < 9) ? tap / 3 : 0;
    int dx = (tap < 9) ? tap % 3 : 0;
    bf16x8 af = *reinterpret_cast<const bf16x8*>(&lds[dy][p0 + col + dx][ci0]);
    bf16x8 b0 = *reinterpret_cast<const bf16x8*>(wt2 + ((size_t)tap * 32 + col) * 16 + ci0);
    bf16x8 b1 = *reinterpret_cast<const bf16x8*>(wt2 + ((size_t)tap * 32 + 16 + col) * 16 + ci0);
    acc0 = __builtin_amdgcn_mfma_f32_16x16x32_bf16(af, b0, acc0, 0, 0, 0);
    acc1 = __builtin_amdgcn_mfma_f32_16x16x32_bf16(af, b1, acc1, 0, 0, 0);
  }
  int px = p0 + kg * 4;
  ushort4 o0, o1;
  o0.x = f2bf(acc0[0]); o0.y = f2bf(acc0[1]); o0.z = f2bf(acc0[2]); o0.w = f2bf(acc0[3]);
  o1.x = f2bf(acc1[0]); o1.y = f2bf(acc1[1]); o1.z = f2bf(acc1[2]); o1.w = f2bf(acc1[3]);
  *reinterpret_cast<ushort4*>(outp + ((size_t)(b * 32 + col) * 64 + y) * 64 + px) = o0;
  *reinterpret_cast<ushort4*>(outp + ((size_t)(b * 32 + 16 + col) * 64 + y) * 64 + px) = o1;
}

// ---------------- conv3 via MFMA: CIN=32, COUT=64, HW=32; BN2+ReLU+maxpool fused at staging ----------------
__global__ __launch_bounds__(256)
void k_conv3_mfma(const unsigned short* __restrict__ in, const unsigned short* __restrict__ wt3,
                  const float* __restrict__ bnpart, const float* __restrict__ bng,
                  const float* __restrict__ bnb, unsigned short* __restrict__ outp) {
  const int b = blockIdx.x, y0 = blockIdx.y * 2;
  const int tid = threadIdx.x;
  const int w = tid >> 6, lane = tid & 63;
  const int col = lane & 15, kg = lane >> 4;
  const int yloc = w >> 1, p0 = (w & 1) * 16;
  __shared__ unsigned short lds[4][34][40];
  __shared__ float2 ssl[32];
  bn_ssl(ssl, bnpart, bng, bnb, 32, 32, 1.f / (float)(B_ * 4096));
  __syncthreads();
  for (int i = tid; i < 4 * 34 * 32; i += 256) {
    int px = i % 34, row = (i / 34) % 4, ci = i / 136;
    int gy = y0 + row - 1, gx = px - 1;
    float v = 0.f;
    if (gy >= 0 && gy < 32 && gx >= 0 && gx < 32) {
      float2 s = ssl[ci];
      size_t base = ((size_t)(b * 32 + ci) * 64 + 2 * gy) * 64 + 2 * gx;
      float r0 = fmaf(bf2f(in[base]),      s.x, s.y);
      float r1 = fmaf(bf2f(in[base + 1]),  s.x, s.y);
      float r2 = fmaf(bf2f(in[base + 64]), s.x, s.y);
      float r3 = fmaf(bf2f(in[base + 65]), s.x, s.y);
      v = fmaxf(fmaxf(fmaxf(r0, r1), fmaxf(r2, r3)), 0.f);
    }
    lds[row][px][ci] = f2bf(v);
  }
  __syncthreads();
  f32x4 acc[4];
  #pragma unroll
  for (int c = 0; c < 4; ++c) acc[c] = (f32x4){0.f, 0.f, 0.f, 0.f};
  #pragma unroll
  for (int tap = 0; tap < 9; ++tap) {
    int dy = tap / 3, dx = tap % 3;
    bf16x8 af = *reinterpret_cast<const bf16x8*>(&lds[yloc + dy][p0 + col + dx][kg * 8]);
    #pragma unroll
    for (int c = 0; c < 4; ++c) {
      bf16x8 bfr = *reinterpret_cast<const bf16x8*>(wt3 + ((size_t)tap * 64 + c * 16 + col) * 32 + kg * 8);
      acc[c] = __builtin_amdgcn_mfma_f32_16x16x32_bf16(af, bfr, acc[c], 0, 0, 0);
    }
  }
  int yy = y0 + yloc, px = p0 + kg * 4;
  #pragma unroll
  for (int c = 0; c < 4; ++c) {
    ushort4 o;
    o.x = f2bf(acc[c][0]); o.y = f2bf(acc[c][1]); o.z = f2bf(acc[c][2]); o.w = f2bf(acc[c][3]);
    *reinterpret_cast<ushort4*>(outp + ((size_t)(b * 64 + c * 16 + col) * 32 + yy) * 32 + px) = o;
  }
}

// ---------------- conv4 via MFMA: CIN=64, COUT=64, HW=16; BN3+ReLU+maxpool fused at staging ----------------
__global__ __launch_bounds__(128)
void k_conv4_mfma(const unsigned short* __restrict__ in, const unsigned short* __restrict__ wt4,
                  const float* __restrict__ bnpart, const float* __restrict__ bng,
                  const float* __restrict__ bnb, unsigned short* __restrict__ outp) {
  const int b = blockIdx.x, y0 = blockIdx.y * 2;
  const int tid = threadIdx.x;
  const int w = tid >> 6, lane = tid & 63;
  const int col = lane & 15, kg = lane >> 4;
  __shared__ unsigned short lds[4][18][72];
  __shared__ float2 ssl[64];
  bn_ssl(ssl, bnpart, bng, bnb, 64, 16, 1.f / (float)(B_ * 1024));
  __syncthreads();
  for (int i = tid; i < 4 * 18 * 64; i += 128) {
    int px = i % 18, row = (i / 18) % 4, ci = i / 72;
    int gy = y0 + row - 1, gx = px - 1;
    float v = 0.f;
    if (gy >= 0 && gy < 16 && gx >= 0 && gx < 16) {
      float2 s = ssl[ci];
      size_t base = ((size_t)(b * 64 + ci) * 32 + 2 * gy) * 32 + 2 * gx;
      float r0 = fmaf(bf2f(in[base]),      s.x, s.y);
      float r1 = fmaf(bf2f(in[base + 1]),  s.x, s.y);
      float r2 = fmaf(bf2f(in[base + 32]), s.x, s.y);
      float r3 = fmaf(bf2f(in[base + 33]), s.x, s.y);
      v = fmaxf(fmaxf(fmaxf(r0, r1), fmaxf(r2, r3)), 0.f);
    }
    lds[row][px][ci] = f2bf(v);
  }
  __syncthreads();
  f32x4 acc[4];
  #pragma unroll
  for (int c = 0; c < 4; ++c) acc[c] = (f32x4){0.f, 0.f, 0.f, 0.f};
  #pragma unroll
  for (int tap = 0; tap < 9; ++tap) {
    int dy = tap / 3, dx = tap % 3;
    #pragma unroll
    for (int kc = 0; kc < 2; ++kc) {
      bf16x8 af = *reinterpret_cast<const bf16x8*>(&lds[w + dy][col + dx][kc * 32 + kg * 8]);
      #pragma unroll
      for (int c = 0; c < 4; ++c) {
        bf16x8 bfr = *reinterpret_cast<const bf16x8*>(wt4 + ((size_t)tap * 64 + c * 16 + col) * 64 + kc * 32 + kg * 8);
        acc[c] = __builtin_amdgcn_mfma_f32_16x16x32_bf16(af, bfr, acc[c], 0, 0, 0);
      }
    }
  }
  int yy = y0 + w, px = kg * 4;
  #pragma unroll
  for (int c = 0; c < 4; ++c) {
    ushort4 o;
    o.x = f2bf(acc[c][0]); o.y = f2bf(acc[c][1]); o.z = f2bf(acc[c][2]); o.w = f2bf(acc[c][3]);
    *reinterpret_cast<ushort4*>(outp + ((size_t)(b * 64 + c * 16 + col) * 16 + yy) * 16 + px) = o;
  }
}

// ---------------- BatchNorm stats on bf16 tensor (paired loads) ----------------
template<int C, int HW2>
__global__ __launch_bounds__(256)
void k_bn_stats_bf(const unsigned short* __restrict__ x, float* __restrict__ part) {
  int c = blockIdx.x, s = blockIdx.y, ns = gridDim.y;
  const int Np2 = B_ * HW2 / 2;
  float s1 = 0.f, s2 = 0.f;
  for (int ii = s * 256 + threadIdx.x; ii < Np2; ii += ns * 256) {
    int b = ii / (HW2 / 2), p2 = ii % (HW2 / 2);
    const unsigned short* pp = x + ((size_t)b * C + c) * HW2 + p2 * 2;
    unsigned u = *reinterpret_cast<const unsigned*>(pp);
    float v0 = __uint_as_float(u << 16);
    float v1 = __uint_as_float(u & 0xFFFF0000u);
    s1 += v0 + v1; s2 += v0 * v0 + v1 * v1;
  }
  __shared__ float r1[256], r2[256];
  r1[threadIdx.x] = s1; r2[threadIdx.x] = s2; __syncthreads();
  for (int off = 128; off > 0; off >>= 1) {
    if (threadIdx.x < off) { r1[threadIdx.x] += r1[threadIdx.x + off]; r2[threadIdx.x] += r2[threadIdx.x + off]; }
    __syncthreads();
  }
  if (threadIdx.x == 0) {
    part[(c * ns + s) * 2 + 0] = r1[0];
    part[(c * ns + s) * 2 + 1] = r2[0];
  }
}

// ---------------- bn4(folded) + relu + avg pool from bf16 ----------------
__global__ __launch_bounds__(256)
void k_avgpool_bn_bf(const unsigned short* __restrict__ x, const float* __restrict__ bnpart,
                     const float* __restrict__ g, const float* __restrict__ bb,
                     float* __restrict__ outp) {
  __shared__ float2 ssl[64];
  bn_ssl(ssl, bnpart, g, bb, 64, 8, 1.f / (float)(B_ * 256));
  __syncthreads();
  int idx = blockIdx.x * 256 + threadIdx.x;
  int b = idx >> 8;
  int r = idx & 255;
  int c = r >> 2, i = (r >> 1) & 1, j = r & 1;
  float2 s = ssl[c];
  const unsigned short* p = x + ((size_t)(b * 64 + c) * 16 + i * 8) * 16 + j * 8;
  float sum = 0.f;
  #pragma unroll
  for (int yy = 0; yy < 8; ++yy)
    #pragma unroll
    for (int xx = 0; xx < 8; ++xx)
      sum += fmaxf(fmaf(bf2f(p[yy * 16 + xx]), s.x, s.y), 0.f);
  outp[idx] = sum * (1.f / 64.f);
}

// ---------------- split-K GEMM: A(64 x K) @ W(K x NOUT) -> partials (fp32, encoder) ----------------
template<int K, int NOUT>
__global__ __launch_bounds__(256)
void k_gemm_part(const float* __restrict__ A, const float* __restrict__ W, int ldw,
                 float* __restrict__ part) {
  int jt = blockIdx.x, ks = blockIdx.y;
  int k0 = ks * 64;
  __shared__ float As[64][65];
  for (int i = threadIdx.x; i < 4096; i += 256) {
    int r = i >> 6, c = i & 63;
    As[r][c] = A[(size_t)r * K + k0 + c];
  }
  __syncthreads();
  int jsub = threadIdx.x & 31;
  int bg = threadIdx.x >> 5;
  int j = jt * 32 + jsub;
  float acc[8] = {0.f, 0.f, 0.f, 0.f, 0.f, 0.f, 0.f, 0.f};
  const float* wp = W + (size_t)k0 * ldw + j;
  #pragma unroll 8
  for (int kk = 0; kk < 64; ++kk) {
    float w = wp[(size_t)kk * ldw];
    #pragma unroll
    for (int r = 0; r < 8; ++r) acc[r] = fmaf(As[bg * 8 + r][kk], w, acc[r]);
  }
  float* pp = part + (size_t)ks * 64 * NOUT + j;
  #pragma unroll
  for (int r = 0; r < 8; ++r) pp[(size_t)(bg * 8 + r) * NOUT] = acc[r];
}

// ---------------- reduce partials + bias (+GLU) (+LN) ----------------
template<int NOUT, int NO_FIN, int KS, bool GLU_, bool LN_>
__global__ __launch_bounds__(256)
void k_fc_reduce(const float* __restrict__ part, const float* __restrict__ bias, int bstride,
                 const float* __restrict__ lng, const float* __restrict__ lnb,
                 float* __restrict__ outp) {
  constexpr int R = (NO_FIN + 255) / 256;
  int b = blockIdx.x, t = threadIdx.x;
  const float* bp = bias + (size_t)b * bstride;
  float v[R];
  #pragma unroll
  for (int r = 0; r < R; ++r) {
    int j = t + r * 256;
    if (j < NO_FIN) {
      float za = bp[j];
      float zb = GLU_ ? bp[j + NO_FIN] : 0.f;
      #pragma unroll
      for (int ks = 0; ks < KS; ++ks) {
        const float* pr = part + ((size_t)ks * 64 + b) * NOUT;
        za += pr[j];
        if (GLU_) zb += pr[j + NO_FIN];
      }
      v[r] = GLU_ ? za * sigmoidf_(zb) : za;
    } else v[r] = 0.f;
  }
  if (LN_) {
    __shared__ float red[256];
    float s1 = 0.f, s2 = 0.f;
    #pragma unroll
    for (int r = 0; r < R; ++r) { s1 += v[r]; s2 += v[r] * v[r]; }
    s1 = blockReduceSum(s1, red);
    s2 = blockReduceSum(s2, red);
    float mu = s1 / (float)NO_FIN;
    float rstd = rsqrtf(s2 / (float)NO_FIN - mu * mu + 1e-5f);
    #pragma unroll
    for (int r = 0; r < R; ++r) {
      int j = t + r * 256;
      if (j < NO_FIN) outp[(size_t)b * NO_FIN + j] = fmaf((v[r] - mu) * rstd, lng[j], lnb[j]);
    }
  } else {
    #pragma unroll
    for (int r = 0; r < R; ++r) {
      int j = t + r * 256;
      if (j < NO_FIN) outp[(size_t)b * NO_FIN + j] = v[r];
    }
  }
}

// ---------------- per-tick syn GEMM via MFMA, full K, GLU fused ----------------
// grid(32), block 256 = 4 waves. Waves 0-1: low j cols (blockIdx*32 + 0..31);
// waves 2-3: paired high cols (+1024). Full K=1024 chain (32 MFMAs).
// Emits v[n][b] (post-GLU) and deterministic per-block LN partial stats
// part2[b][32] (float2: sum, sumsq over this block's 32 n).
__global__ __launch_bounds__(256)
void k_syn_mfma2(const unsigned short* __restrict__ Abf, const unsigned short* __restrict__ Bt,
                 const float* __restrict__ syncst, float* __restrict__ vout,
                 float* __restrict__ part2f) {
  __shared__ float zsh[2][32][64];
  __shared__ float vsh[32][64];
  const int w = threadIdx.x >> 6, lane = threadIdx.x & 63;
  const int col = lane & 15, kg = lane >> 4;
  const int hi = w >> 1;
  const int nl = (w & 1) * 16 + col;
  const int jcol = hi * 1024 + blockIdx.x * 32 + nl;
  f32x4 acc[4];
  #pragma unroll
  for (int mt = 0; mt < 4; ++mt) acc[mt] = (f32x4){0.f, 0.f, 0.f, 0.f};
  #pragma unroll 4
  for (int kb = 0; kb < 32; ++kb) {
    const int kk = kb * 32 + kg * 8;
    bf16x8 bfr = *reinterpret_cast<const bf16x8*>(Bt + (size_t)jcol * 1024 + kk);
    #pragma unroll
    for (int mt = 0; mt < 4; ++mt) {
      bf16x8 a = *reinterpret_cast<const bf16x8*>(Abf + (size_t)(mt * 16 + col) * 1024 + kk);
      acc[mt] = __builtin_amdgcn_mfma_f32_16x16x32_bf16(a, bfr, acc[mt], 0, 0, 0);
    }
  }
  // D layout: col=lane&15 (j), row=(lane>>4)*4+reg (b)
  #pragma unroll
  for (int mt = 0; mt < 4; ++mt) {
    int b0 = mt * 16 + kg * 4;
    #pragma unroll
    for (int r = 0; r < 4; ++r)
      zsh[hi][nl][b0 + r] = acc[mt][r];
  }
  __syncthreads();
  #pragma unroll
  for (int q = 0; q < 8; ++q) {
    int idx = threadIdx.x + q * 256;
    int nloc = idx >> 6, b = idx & 63;
    int n = blockIdx.x * 32 + nloc;
    float za = zsh[0][nloc][b] + syncst[b * 2048 + n];
    float zb = zsh[1][nloc][b] + syncst[b * 2048 + 1024 + n];
    float v = za * sigmoidf_(zb);
    vout[n * 64 + b] = v;
    vsh[nloc][b] = v;
  }
  __syncthreads();
  if (threadIdx.x < 64) {
    int b = threadIdx.x;
    float s1 = 0.f, s2 = 0.f;
    #pragma unroll
    for (int i = 0; i < 32; ++i) { float v = vsh[i][b]; s1 += v; s2 += v * v; }
    float2* p2 = reinterpret_cast<float2*>(part2f);
    p2[b * 32 + blockIdx.x] = make_float2(s1, s2);
  }
}

// ---------------- recurrent state init ----------------
__global__ __launch_bounds__(256)
void k_init(const float* __restrict__ sa, const float* __restrict__ st,
            const int* __restrict__ oL, const int* __restrict__ oR,
            float* __restrict__ act, unsigned short* __restrict__ act_bf,
            unsigned short* __restrict__ trace,
            float* __restrict__ ao, float* __restrict__ bo) {
  int idx = blockIdx.x * 256 + threadIdx.x;
  if (idx < B_ * N_ * M_) {
    int n = idx >> 11, m = idx & 31;
    trace[idx] = f2bf(st[n * 32 + m]);
  }
  if (idx < B_ * N_) {
    float v = sa[idx % N_];
    act[idx] = v;
    act_bf[idx] = f2bf(v);
  }
  if (idx < B_ * NSO_) {
    int i = idx % NSO_;
    ao[idx] = sa[oL[i]] * sa[oR[i]];
    bo[idx] = 1.f;
  }
}

// ---------------- per-tick: per-neuron private MLP via MFMA; LN of current slot fused ----------------
// Stats: sum 32 deterministic partials per b=lane; LN-transform v[n][b]; patch LDS ring
// slot `tick` and persist bf16 to global trace for future ticks.
__global__ __launch_bounds__(128)
void k_nlm_mfma(unsigned short* __restrict__ trace, const unsigned short* __restrict__ w1t,
                const float* __restrict__ vout, const float* __restrict__ part2f,
                const float* __restrict__ lng, const float* __restrict__ lnb,
                const float* __restrict__ b1, const float* __restrict__ w2,
                const float* __restrict__ b2, float* __restrict__ act,
                unsigned short* __restrict__ act_bf, int tick) {
  const int w = threadIdx.x >> 6, lane = threadIdx.x & 63;
  const int n = blockIdx.x * 2 + w;
  const int col = lane & 15, kg = lane >> 4;
  __shared__ __align__(16) unsigned short ldsA[2][64][40];
  {
    const float2* p2 = reinterpret_cast<const float2*>(part2f);
    float s1 = 0.f, s2 = 0.f;
    #pragma unroll
    for (int i = 0; i < 32; ++i) { float2 pv = p2[lane * 32 + i]; s1 += pv.x; s2 += pv.y; }
    float mu = s1 * (1.f / 1024.f);
    float rstd = rsqrtf(s2 * (1.f / 1024.f) - mu * mu + 1e-5f);
    float vv = vout[n * 64 + lane];
    unsigned short vbf = f2bf(fmaf((vv - mu) * rstd, lng[n], lnb[n]));
    const uint4* src = reinterpret_cast<const uint4*>(trace + ((size_t)n * 64 + lane) * 32);
    uint4 r0 = src[0], r1 = src[1], r2 = src[2], r3 = src[3];
    uint4* d = reinterpret_cast<uint4*>(&ldsA[w][lane][0]);
    d[0] = r0; d[1] = r1; d[2] = r2; d[3] = r3;
    ldsA[w][lane][tick] = vbf;                                  // patch current ring slot
    trace[((size_t)n * 64 + lane) * 32 + tick] = vbf;           // persist for future ticks
  }
  bf16x8 bf[16];
  float b1v[16], w2v[8];
  #pragma unroll
  for (int nt = 0; nt < 16; ++nt) {
    bf[nt] = *reinterpret_cast<const bf16x8*>(w1t + (((size_t)n * 256 + nt * 16 + col) * 32 + kg * 8));
    b1v[nt] = b1[n * 256 + nt * 16 + col];
  }
  #pragma unroll
  for (int nt = 0; nt < 8; ++nt) w2v[nt] = w2[n * 128 + nt * 16 + col];
  const float b2n = b2[n];
  const int kbase = kg * 8 + ((tick + 1) & 31);
  __syncthreads();
  #pragma unroll
  for (int mt = 0; mt < 4; ++mt) {
    const int brow = mt * 16 + col;
    bf16x8 af;
    #pragma unroll
    for (int j = 0; j < 8; ++j)
      af[j] = (short)ldsA[w][brow][(kbase + j) & 31];
    f32x4 acc[16];
    #pragma unroll
    for (int nt = 0; nt < 16; ++nt)
      acc[nt] = __builtin_amdgcn_mfma_f32_16x16x32_bf16(af, bf[nt], (f32x4){0.f, 0.f, 0.f, 0.f}, 0, 0, 0);
    float v0 = 0.f, v1 = 0.f, v2 = 0.f, v3 = 0.f;
    #pragma unroll
    for (int nt = 0; nt < 8; ++nt) {
      f32x4 za = acc[nt], zb = acc[nt + 8];
      float ba = b1v[nt], bg = b1v[nt + 8], wv = w2v[nt];
      v0 = fmaf((za[0] + ba) * sigmoidf_(zb[0] + bg), wv, v0);
      v1 = fmaf((za[1] + ba) * sigmoidf_(zb[1] + bg), wv, v1);
      v2 = fmaf((za[2] + ba) * sigmoidf_(zb[2] + bg), wv, v2);
      v3 = fmaf((za[3] + ba) * sigmoidf_(zb[3] + bg), wv, v3);
    }
    #pragma unroll
    for (int o = 1; o <= 8; o <<= 1) {
      v0 += __shfl_xor(v0, o); v1 += __shfl_xor(v1, o);
      v2 += __shfl_xor(v2, o); v3 += __shfl_xor(v3, o);
    }
    if (col == 0) {
      int b0 = mt * 16 + kg * 4;
      float r0 = v0 + b2n, r1 = v1 + b2n, r2 = v2 + b2n, r3 = v3 + b2n;
      act[(size_t)(b0 + 0) * 1024 + n] = r0;
      act[(size_t)(b0 + 1) * 1024 + n] = r1;
      act[(size_t)(b0 + 2) * 1024 + n] = r2;
      act[(size_t)(b0 + 3) * 1024 + n] = r3;
      act_bf[(size_t)(b0 + 0) * 1024 + n] = f2bf(r0);
      act_bf[(size_t)(b0 + 1) * 1024 + n] = f2bf(r1);
      act_bf[(size_t)(b0 + 2) * 1024 + n] = f2bf(r2);
      act_bf[(size_t)(b0 + 3) * 1024 + n] = f2bf(r3);
    }
  }
}

// ---------------- per-tick: sync_o + output MLP + pred + cert (1024 thr, split-K phases) ----------------
__global__ __launch_bounds__(1024)
void k_outpath(const float* __restrict__ act, float* __restrict__ ao, float* __restrict__ bo,
               const float* __restrict__ dec_o, const int* __restrict__ oL, const int* __restrict__ oR,
               const float* __restrict__ opw1, const float* __restrict__ opb1,
               const float* __restrict__ l1g, const float* __restrict__ l1b,
               const float* __restrict__ opw2, const float* __restrict__ opb2,
               const float* __restrict__ l2g, const float* __restrict__ l2b,
               const float* __restrict__ opw3, const float* __restrict__ opb3,
               float* __restrict__ outp, int tick) {
  int b = blockIdx.x, t = threadIdx.x;
  __shared__ float red[16];
  __shared__ float syo[256], h1s[256], h2s[64];
  __shared__ float zp1[4][256];
  __shared__ float zp2[16][64];
  const float* actb = act + (size_t)b * 1024;
  if (t < 256) {
    float po = actb[oL[t]] * actb[oR[t]];
    float r = __expf(-fminf(fmaxf(dec_o[t], 0.f), 15.f));
    int ai = b * 256 + t;
    float av = fmaf(r, ao[ai], po);
    float bv = fmaf(r, bo[ai], 1.f);
    ao[ai] = av; bo[ai] = bv;
    syo[t] = av * rsqrtf(bv + 1e-8f);
  }
  __syncthreads();
  {
    int j = t & 255, ks = t >> 8;
    float z = 0.f;
    const float* wcol = opw1 + j;
    #pragma unroll 8
    for (int k = ks * 64; k < ks * 64 + 64; ++k) z = fmaf(syo[k], wcol[k * 256], z);
    zp1[ks][j] = z;
  }
  __syncthreads();
  float h1v = 0.f;
  if (t < 256) h1v = zp1[0][t] + zp1[1][t] + zp1[2][t] + zp1[3][t] + opb1[t];
  float s1 = bsum<16>(t < 256 ? h1v : 0.f, red);
  float s2 = bsum<16>(t < 256 ? h1v * h1v : 0.f, red);
  if (t < 256) {
    float mu = s1 * (1.f / 256.f);
    float rstd = rsqrtf(s2 * (1.f / 256.f) - mu * mu + 1e-5f);
    h1s[t] = fmaxf(fmaf((h1v - mu) * rstd, l1g[t], l1b[t]), 0.f);
  }
  __syncthreads();
  {
    int j = t & 63, ks = t >> 6;
    float z = 0.f;
    const float* wcol = opw2 + j;
    #pragma unroll
    for (int k = ks * 16; k < ks * 16 + 16; ++k) z = fmaf(h1s[k], wcol[k * 64], z);
    zp2[ks][j] = z;
  }
  __syncthreads();
  if (t < 64) {
    float z2 = opb2[t];
    #pragma unroll
    for (int ks = 0; ks < 16; ++ks) z2 += zp2[ks][t];
    float a1 = z2, a2 = z2 * z2;
    #pragma unroll
    for (int o = 32; o > 0; o >>= 1) { a1 += __shfl_xor(a1, o); a2 += __shfl_xor(a2, o); }
    float mu2 = a1 * (1.f / 64.f);
    float rs2 = rsqrtf(a2 * (1.f / 64.f) - mu2 * mu2 + 1e-5f);
    h2s[t] = fmaxf(fmaf((z2 - mu2) * rs2, l2g[t], l2b[t]), 0.f);
  }
  __syncthreads();
  float z3 = 0.f;
  if (t < OUT_) {
    z3 = opb3[t];
    const float* wcol = opw3 + t;
    #pragma unroll 8
    for (int k = 0; k < 64; ++k) z3 = fmaf(h2s[k], wcol[k * OUT_], z3);
    outp[(size_t)b * (OUT_ * T_) + (size_t)t * T_ + tick] = z3;
  }
  float mx = bmax<16>(t < OUT_ ? z3 : -INFINITY, red);
  float e = (t < OUT_) ? __expf(z3 - mx) : 0.f;
  float S = bsum<16>(e, red);
  float inv = 1.f / S;
  float ep = 0.f;
  if (t < OUT_) {
    float p = e * inv;
    ep = p * __logf(p + 1e-10f);
  }
  float ent = -bsum<16>(ep, red);
  if (t == 0) {
    float ne = ent * (1.f / logf(1000.f));
    outp[(size_t)B_ * OUT_ * T_ + (size_t)b * 2 * T_ + tick]      = ne;
    outp[(size_t)B_ * OUT_ * T_ + (size_t)b * 2 * T_ + T_ + tick] = 1.f - ne;
  }
}

extern "C" void kernel_launch(void* const* d_in, const int* in_sizes, int n_in,
                              void* d_out, int out_size, void* d_ws, size_t ws_size,
                              hipStream_t stream) {
  (void)in_sizes; (void)n_in; (void)out_size; (void)ws_size;
  const float* x      = (const float*)d_in[0];
  const float* c1w    = (const float*)d_in[1];
  const float* bn1g   = (const float*)d_in[3];
  const float* bn1b   = (const float*)d_in[4];
  const float* c2w    = (const float*)d_in[5];
  const float* bn2g   = (const float*)d_in[7];
  const float* bn2b   = (const float*)d_in[8];
  const float* c3w    = (const float*)d_in[9];
  const float* bn3g   = (const float*)d_in[11];
  const float* bn3b   = (const float*)d_in[12];
  const float* c4w    = (const float*)d_in[13];
  const float* bn4g   = (const float*)d_in[15];
  const float* bn4b   = (const float*)d_in[16];
  const float* fc1w   = (const float*)d_in[17];
  const float* fc1b   = (const float*)d_in[18];
  const float* fc2w   = (const float*)d_in[19];
  const float* fc2b   = (const float*)d_in[20];
  const float* kvw    = (const float*)d_in[21];
  const float* kvb    = (const float*)d_in[22];
  const float* kvlg   = (const float*)d_in[23];
  const float* kvlb   = (const float*)d_in[24];
  const float* synw   = (const float*)d_in[25];
  const float* synb   = (const float*)d_in[26];
  const float* synlg  = (const float*)d_in[27];
  const float* synlb  = (const float*)d_in[28];
  const float* nlmw1  = (const float*)d_in[29];
  const float* nlmb1  = (const float*)d_in[30];
  const float* nlmw2  = (const float*)d_in[31];
  const float* nlmb2  = (const float*)d_in[32];
  const float* sact   = (const float*)d_in[33];
  const float* strc   = (const float*)d_in[34];
  const float* dec_o  = (const float*)d_in[36];
  const float* attn_inw = (const float*)d_in[39];
  const float* attn_inb = (const float*)d_in[40];
  const float* attn_ow  = (const float*)d_in[41];
  const float* attn_ob  = (const float*)d_in[42];
  const float* opw1   = (const float*)d_in[43];
  const float* opb1   = (const float*)d_in[44];
  const float* opl1g  = (const float*)d_in[45];
  const float* opl1b  = (const float*)d_in[46];
  const float* opw2   = (const float*)d_in[47];
  const float* opb2   = (const float*)d_in[48];
  const float* opl2g  = (const float*)d_in[49];
  const float* opl2b  = (const float*)d_in[50];
  const float* opw3   = (const float*)d_in[51];
  const float* opb3   = (const float*)d_in[52];
  const int*   oL     = (const int*)d_in[55];
  const int*   oR     = (const int*)d_in[56];
  float* outp = (float*)d_out;
  float* ws   = (float*)d_ws;

  // workspace (float offsets), R15/R17 layout (measured 527 us).
  unsigned short* c1raw_bf = (unsigned short*)(ws + 8388608);
  unsigned short* c2raw_bf = (unsigned short*)ws;
  unsigned short* c3raw_bf = (unsigned short*)(ws + 8388608);
  unsigned short* c4raw_bf = (unsigned short*)ws;
  float* part  = ws + 4194304;
  float* vout  = ws + 4194304;                 // 65,536 fl (tick v buffer; aliases part, post-encoder)
  float* part2f= ws + 4259840;                 // 4,096 fl (64 b x 32 blk float2)
  unsigned short* trace_bf = (unsigned short*)(ws + 6291456);
  float* act   = ws + 8388608;
  float* syncst= ws + 8454144;
  float* pooled= ws + 8585216;
  float* ench  = ws + 8601600;
  float* enc   = ws + 8609792;
  float* kvbuf = ws + 8642560;
  float* vhbuf = ws + 8675328;
  float* aout  = ws + 8708096;
  float* ao    = ws + 8740864;
  float* bo    = ws + 8757248;
  unsigned short* w1t_bf   = (unsigned short*)(ws + 8777728);
  unsigned short* synw2t_bf= (unsigned short*)(ws + 12972032);
  unsigned short* wt2 = (unsigned short*)(ws + 14061568);
  unsigned short* wt3 = (unsigned short*)(ws + 14064128);
  unsigned short* wt4 = (unsigned short*)(ws + 14073344);
  float* bnpart = ws + 14091776;
  unsigned short* act_bf = (unsigned short*)(ws + 14095872);

  // ---- conv weights -> bf16 tap-major ----
  k_wprep<<<236,256,0,stream>>>(c2w, c3w, c4w, wt2, wt3, wt4);

  // ---- encoder convs (BN finalize + apply + pool fused into staging; MFMA compute) ----
  k_conv1<<<dim3(64,16),256,0,stream>>>(x, c1w, c1raw_bf);
  k_bn_stats_bf<16,4096><<<dim3(16,32),256,0,stream>>>(c1raw_bf, bnpart);

  k_conv2_mfma<<<dim3(64,64),256,0,stream>>>(c1raw_bf, wt2, bnpart, bn1g, bn1b, c2raw_bf);
  k_bn_stats_bf<32,4096><<<dim3(32,32),256,0,stream>>>(c2raw_bf, bnpart);

  k_conv3_mfma<<<dim3(64,16),256,0,stream>>>(c2raw_bf, wt3, bnpart, bn2g, bn2b, c3raw_bf);
  k_bn_stats_bf<64,1024><<<dim3(64,16),256,0,stream>>>(c3raw_bf, bnpart);

  k_conv4_mfma<<<dim3(64,8),128,0,stream>>>(c3raw_bf, wt4, bnpart, bn3g, bn3b, c4raw_bf);

  k_w1t<<<1024,256,0,stream>>>(nlmw1, w1t_bf);
  k_synwt<<<dim3(32,16),256,0,stream>>>(synw + (size_t)512 * 2048, synw2t_bf);

  k_bn_stats_bf<64,256><<<dim3(64,8),256,0,stream>>>(c4raw_bf, bnpart);
  k_avgpool_bn_bf<<<64,256,0,stream>>>(c4raw_bf, bnpart, bn4g, bn4b, pooled);

  // ---- encoder FC chain (split-K GEMM + fused reduce; many-block structure) ----
  k_gemm_part<256,256><<<dim3(8,4),256,0,stream>>>(pooled, fc1w, 256, part);
  k_fc_reduce<256,128,4,true,false><<<64,256,0,stream>>>(part, fc1b, 0, nullptr, nullptr, ench);
  k_gemm_part<128,512><<<dim3(16,2),256,0,stream>>>(ench, fc2w, 512, part);
  k_fc_reduce<512,512,2,false,false><<<64,256,0,stream>>>(part, fc2b, 0, nullptr, nullptr, enc);
  k_gemm_part<512,512><<<dim3(16,8),256,0,stream>>>(enc, kvw, 512, part);
  k_fc_reduce<512,512,8,false,true><<<64,256,0,stream>>>(part, kvb, 0, kvlg, kvlb, kvbuf);
  // vh = kv @ Wv + bv (attention softmax over single key == 1 -> q,k branches dead)
  k_gemm_part<512,512><<<dim3(16,8),256,0,stream>>>(kvbuf, attn_inw + 1024, 1536, part);
  k_fc_reduce<512,512,8,false,false><<<64,256,0,stream>>>(part, attn_inb + 1024, 0, nullptr, nullptr, vhbuf);
  k_gemm_part<512,512><<<dim3(16,8),256,0,stream>>>(vhbuf, attn_ow, 512, part);
  k_fc_reduce<512,512,8,false,false><<<64,256,0,stream>>>(part, attn_ob, 0, nullptr, nullptr, aout);
  k_gemm_part<512,2048><<<dim3(64,8),256,0,stream>>>(aout, synw, 2048, part);
  k_fc_reduce<2048,2048,8,false,false><<<64,256,0,stream>>>(part, synb, 0, nullptr, nullptr, syncst);

  k_init<<<8192,256,0,stream>>>(sact, strc, oL, oR, act, act_bf, trace_bf, ao, bo);

  // ---- recurrent ticks (3 kernels/tick) ----
  for (int t = 0; t < T_; ++t) {
    k_syn_mfma2<<<32,256,0,stream>>>(act_bf, synw2t_bf, syncst, vout, part2f);
    k_nlm_mfma<<<512,128,0,stream>>>(trace_bf, w1t_bf, vout, part2f, synlg, synlb,
                                     nlmb1, nlmw2, nlmb2, act, act_bf, t);
    k_outpath<<<64,1024,0,stream>>>(act, ao, bo, dec_o, oL, oR,
                                    opw1, opb1, opl1g, opl1b,
                                    opw2, opb2, opl2g, opl2b,
                                    opw3, opb3, outp, t);
  }
}

// Round 24
// 524.777 us; speedup vs baseline: 1.2035x; 1.2035x over previous
//
#include <hip/hip_runtime.h>
#include <math.h>

// Problem constants
constexpr int B_ = 64, N_ = 1024, M_ = 32, T_ = 8;
constexpr int OUT_ = 1000, NSO_ = 256;

#define DEVFN __device__ __forceinline__

typedef __attribute__((ext_vector_type(8))) short bf16x8;
typedef __attribute__((ext_vector_type(4))) float f32x4;

DEVFN float blockReduceSum(float v, float* buf) {
  int t = threadIdx.x;
  buf[t] = v; __syncthreads();
  for (int off = blockDim.x >> 1; off > 0; off >>= 1) {
    if (t < off) buf[t] += buf[t + off];
    __syncthreads();
  }
  float r = buf[0];
  __syncthreads();
  return r;
}

DEVFN float sigmoidf_(float x) { return 1.f / (1.f + __expf(-x)); }

DEVFN unsigned short f2bf(float f) {          // RNE float->bf16
  unsigned u = __float_as_uint(f);
  unsigned r = (u + 0x7FFFu + ((u >> 16) & 1u)) >> 16;
  return (unsigned short)r;
}
DEVFN float bf2f(unsigned short h) { return __uint_as_float((unsigned)h << 16); }

// ---- block reductions for wide blocks (NW waves), shuffle + small LDS ----
template<int NW>
DEVFN float bsum(float v, float* red) {
  #pragma unroll
  for (int o = 32; o > 0; o >>= 1) v += __shfl_xor(v, o);
  int w = threadIdx.x >> 6, ln = threadIdx.x & 63;
  if (ln == 0) red[w] = v;
  __syncthreads();
  if (w == 0) {
    float x = (ln < NW) ? red[ln] : 0.f;
    #pragma unroll
    for (int o = 8; o > 0; o >>= 1) x += __shfl_xor(x, o);
    if (ln == 0) red[0] = x;
  }
  __syncthreads();
  float r = red[0];
  __syncthreads();
  return r;
}

template<int NW>
DEVFN float bmax(float v, float* red) {
  #pragma unroll
  for (int o = 32; o > 0; o >>= 1) v = fmaxf(v, __shfl_xor(v, o));
  int w = threadIdx.x >> 6, ln = threadIdx.x & 63;
  if (ln == 0) red[w] = v;
  __syncthreads();
  if (w == 0) {
    float x = (ln < NW) ? red[ln] : -INFINITY;
    #pragma unroll
    for (int o = 8; o > 0; o >>= 1) x = fmaxf(x, __shfl_xor(x, o));
    if (ln == 0) red[0] = x;
  }
  __syncthreads();
  float r = red[0];
  __syncthreads();
  return r;
}

// ---- BN scale/shift from partial stats, computed per-block in LDS ----
DEVFN void bn_ssl(float2* ssl, const float* bnpart, const float* g, const float* bb,
                  int C, int ns, float inv_n) {
  for (int c = threadIdx.x; c < C; c += blockDim.x) {
    float s1 = 0.f, s2 = 0.f;
    for (int s = 0; s < ns; ++s) { s1 += bnpart[(c * ns + s) * 2]; s2 += bnpart[(c * ns + s) * 2 + 1]; }
    float m = s1 * inv_n;
    float var = s2 * inv_n - m * m;
    float rstd = rsqrtf(var + 1e-5f);
    float sc = g[c] * rstd;
    ssl[c] = make_float2(sc, bb[c] - m * sc);
  }
}

// ---------------- conv weight prep: wt2[10][32][16], wt3[9][64][32], wt4[9][64][64] bf16 ----------------
__global__ __launch_bounds__(256)
void k_wprep(const float* __restrict__ c2w, const float* __restrict__ c3w,
             const float* __restrict__ c4w, unsigned short* __restrict__ wt2,
             unsigned short* __restrict__ wt3, unsigned short* __restrict__ wt4) {
  int i = blockIdx.x * 256 + threadIdx.x;
  if (i < 5120) {               // wt2: tap(10) x co(32) x ci(16); tap 9 = zeros
    int tap = i / 512, co = (i / 16) % 32, ci = i & 15;
    wt2[i] = (tap < 9) ? f2bf(c2w[(co * 16 + ci) * 9 + tap]) : 0;
  } else if (i < 5120 + 18432) { // wt3: tap(9) x co(64) x ci(32)
    int j = i - 5120;
    int tap = j / 2048, co = (j / 32) % 64, ci = j & 31;
    wt3[j] = f2bf(c3w[(co * 32 + ci) * 9 + tap]);
  } else if (i < 5120 + 18432 + 36864) { // wt4: tap(9) x co(64) x ci(64)
    int j = i - 5120 - 18432;
    int tap = j / 4096, co = (j / 64) % 64, ci = j & 63;
    wt4[j] = f2bf(c4w[(co * 64 + ci) * 9 + tap]);
  }
}

// ---------------- nlm_w1 [n][32m][256c] fp32 -> [n][256c][32m] bf16 ----------------
__global__ __launch_bounds__(256)
void k_w1t(const float* __restrict__ w1, unsigned short* __restrict__ w1t) {
  int n = blockIdx.x;
  __shared__ float tile[32][260];
  const float* src = w1 + (size_t)n * 8192;
  for (int i = threadIdx.x; i < 8192; i += 256)
    tile[i >> 8][i & 255] = src[i];
  __syncthreads();
  int c = threadIdx.x;
  unsigned short* dst = w1t + ((size_t)n * 256 + c) * 32;
  #pragma unroll
  for (int q = 0; q < 8; ++q) {
    ushort4 o;
    o.x = f2bf(tile[q * 4 + 0][c]); o.y = f2bf(tile[q * 4 + 1][c]);
    o.z = f2bf(tile[q * 4 + 2][c]); o.w = f2bf(tile[q * 4 + 3][c]);
    *reinterpret_cast<ushort4*>(dst + q * 4) = o;
  }
}

// ---------------- synw[512+k][j] fp32 -> synw2t[j][k] bf16 (transpose) ----------------
__global__ __launch_bounds__(256)
void k_synwt(const float* __restrict__ synw2, unsigned short* __restrict__ Bt) {
  int j0 = blockIdx.x * 64, k0 = blockIdx.y * 64;
  __shared__ float tile[64][65];
  for (int i = threadIdx.x; i < 4096; i += 256) {
    int kk = i >> 6, jj = i & 63;
    tile[kk][jj] = synw2[(size_t)(k0 + kk) * 2048 + j0 + jj];
  }
  __syncthreads();
  int jj = threadIdx.x >> 2, kq = (threadIdx.x & 3) * 16;
  unsigned short* dst = Bt + (size_t)(j0 + jj) * 1024 + k0 + kq;
  #pragma unroll
  for (int q = 0; q < 4; ++q) {
    ushort4 o;
    o.x = f2bf(tile[kq + q * 4 + 0][jj]); o.y = f2bf(tile[kq + q * 4 + 1][jj]);
    o.z = f2bf(tile[kq + q * 4 + 2][jj]); o.w = f2bf(tile[kq + q * 4 + 3][jj]);
    *reinterpret_cast<ushort4*>(dst + q * 4) = o;
  }
}

// ---------------- conv1: VALU tiled conv (CIN=3), fp32 in, bf16 out ----------------
__global__ __launch_bounds__(256)
void k_conv1(const float* __restrict__ in, const float* __restrict__ wgl,
             unsigned short* __restrict__ outp) {
  constexpr int HW = 64, TY = 4, XV = 4, XQ = 16, CPT = 4;
  __shared__ __align__(16) float ins[3][TY + 2][HW + 8];
  const int b = blockIdx.x, y0 = blockIdx.y * TY, tid = threadIdx.x;
  const int sp = tid & 63;
  const int cg = __builtin_amdgcn_readfirstlane(tid >> 6);
  const int xq = sp % XQ, yr = sp / XQ, x0 = xq * XV;
  float acc[CPT][XV];
  #pragma unroll
  for (int j = 0; j < CPT; ++j)
    #pragma unroll
    for (int k = 0; k < XV; ++k) acc[j][k] = 0.f;
  constexpr int NEL = 3 * (TY + 2) * (HW + 8);
  for (int i = tid; i < NEL; i += 256) {
    int col = i % (HW + 8), row = (i / (HW + 8)) % (TY + 2), ci = i / ((HW + 8) * (TY + 2));
    int gx = col - 4, gy = y0 + row - 1;
    float v = 0.f;
    if (gx >= 0 && gx < HW && gy >= 0 && gy < HW)
      v = in[((size_t)(b * 3 + ci) * HW + gy) * HW + gx];
    ins[ci][row][col] = v;
  }
  __syncthreads();
  for (int ci = 0; ci < 3; ++ci) {
    const float* wci = wgl + ((size_t)(cg * CPT) * 3 + ci) * 9;
    #pragma unroll
    for (int dy = 0; dy < 3; ++dy) {
      const float* r = &ins[ci][yr + dy][x0 + 4];
      float win[6];
      win[0] = r[-1];
      float4 m = *reinterpret_cast<const float4*>(r);
      win[1] = m.x; win[2] = m.y; win[3] = m.z; win[4] = m.w;
      win[5] = r[4];
      #pragma unroll
      for (int j = 0; j < CPT; ++j) {
        const float* wj = wci + (size_t)j * 27 + dy * 3;
        float w0 = wj[0], w1 = wj[1], w2 = wj[2];
        #pragma unroll
        for (int k = 0; k < XV; ++k)
          acc[j][k] = fmaf(win[k], w0, fmaf(win[k + 1], w1, fmaf(win[k + 2], w2, acc[j][k])));
      }
    }
  }
  #pragma unroll
  for (int j = 0; j < CPT; ++j) {
    unsigned short* op = outp + (((size_t)b * 16 + cg * CPT + j) * HW + y0 + yr) * HW + x0;
    ushort4 o;
    o.x = f2bf(acc[j][0]); o.y = f2bf(acc[j][1]); o.z = f2bf(acc[j][2]); o.w = f2bf(acc[j][3]);
    *reinterpret_cast<ushort4*>(op) = o;
  }
}

// ---------------- conv2 via MFMA: CIN=16, COUT=32, HW=64; BN1+ReLU fused at staging ----------------
__global__ __launch_bounds__(256)
void k_conv2_mfma(const unsigned short* __restrict__ in, const unsigned short* __restrict__ wt2,
                  const float* __restrict__ bnpart, const float* __restrict__ bng,
                  const float* __restrict__ bnb, unsigned short* __restrict__ outp) {
  const int b = blockIdx.x, y = blockIdx.y;
  const int tid = threadIdx.x;
  const int w = tid >> 6, lane = tid & 63;
  const int col = lane & 15, kg = lane >> 4;
  const int p0 = w * 16;
  __shared__ unsigned short lds[3][68][16];
  __shared__ float2 ssl[16];
  bn_ssl(ssl, bnpart, bng, bnb, 16, 32, 1.f / (float)(B_ * 4096));
  __syncthreads();
  for (int i = tid; i < 3 * 66 * 16; i += 256) {
    int px = i % 66, row = (i / 66) % 3, ci = i / 198;
    int gy = y + row - 1, gx = px - 1;
    float v = 0.f;
    if (gy >= 0 && gy < 64 && gx >= 0 && gx < 64) {
      float2 s = ssl[ci];
      v = fmaxf(fmaf(bf2f(in[((size_t)(b * 16 + ci) * 64 + gy) * 64 + gx]), s.x, s.y), 0.f);
    }
    lds[row][px][ci] = f2bf(v);
  }
  __syncthreads();
  f32x4 acc0 = {0.f, 0.f, 0.f, 0.f}, acc1 = {0.f, 0.f, 0.f, 0.f};
  const int tsel = kg >> 1, ci0 = (kg & 1) * 8;
  #pragma unroll
  for (int p = 0; p < 5; ++p) {
    int tap = 2 * p + tsel;
    int dy = (tap < 9) ? tap / 3 : 0;
    int dx = (tap < 9) ? tap % 3 : 0;
    bf16x8 af = *reinterpret_cast<const bf16x8*>(&lds[dy][p0 + col + dx][ci0]);
    bf16x8 b0 = *reinterpret_cast<const bf16x8*>(wt2 + ((size_t)tap * 32 + col) * 16 + ci0);
    bf16x8 b1 = *reinterpret_cast<const bf16x8*>(wt2 + ((size_t)tap * 32 + 16 + col) * 16 + ci0);
    acc0 = __builtin_amdgcn_mfma_f32_16x16x32_bf16(af, b0, acc0, 0, 0, 0);
    acc1 = __builtin_amdgcn_mfma_f32_16x16x32_bf16(af, b1, acc1, 0, 0, 0);
  }
  int px = p0 + kg * 4;
  ushort4 o0, o1;
  o0.x = f2bf(acc0[0]); o0.y = f2bf(acc0[1]); o0.z = f2bf(acc0[2]); o0.w = f2bf(acc0[3]);
  o1.x = f2bf(acc1[0]); o1.y = f2bf(acc1[1]); o1.z = f2bf(acc1[2]); o1.w = f2bf(acc1[3]);
  *reinterpret_cast<ushort4*>(outp + ((size_t)(b * 32 + col) * 64 + y) * 64 + px) = o0;
  *reinterpret_cast<ushort4*>(outp + ((size_t)(b * 32 + 16 + col) * 64 + y) * 64 + px) = o1;
}

// ---------------- conv3 via MFMA: CIN=32, COUT=64, HW=32; BN2+ReLU+maxpool fused at staging ----------------
__global__ __launch_bounds__(256)
void k_conv3_mfma(const unsigned short* __restrict__ in, const unsigned short* __restrict__ wt3,
                  const float* __restrict__ bnpart, const float* __restrict__ bng,
                  const float* __restrict__ bnb, unsigned short* __restrict__ outp) {
  const int b = blockIdx.x, y0 = blockIdx.y * 2;
  const int tid = threadIdx.x;
  const int w = tid >> 6, lane = tid & 63;
  const int col = lane & 15, kg = lane >> 4;
  const int yloc = w >> 1, p0 = (w & 1) * 16;
  __shared__ unsigned short lds[4][34][40];
  __shared__ float2 ssl[32];
  bn_ssl(ssl, bnpart, bng, bnb, 32, 32, 1.f / (float)(B_ * 4096));
  __syncthreads();
  for (int i = tid; i < 4 * 34 * 32; i += 256) {
    int px = i % 34, row = (i / 34) % 4, ci = i / 136;
    int gy = y0 + row - 1, gx = px - 1;
    float v = 0.f;
    if (gy >= 0 && gy < 32 && gx >= 0 && gx < 32) {
      float2 s = ssl[ci];
      size_t base = ((size_t)(b * 32 + ci) * 64 + 2 * gy) * 64 + 2 * gx;
      float r0 = fmaf(bf2f(in[base]),      s.x, s.y);
      float r1 = fmaf(bf2f(in[base + 1]),  s.x, s.y);
      float r2 = fmaf(bf2f(in[base + 64]), s.x, s.y);
      float r3 = fmaf(bf2f(in[base + 65]), s.x, s.y);
      v = fmaxf(fmaxf(fmaxf(r0, r1), fmaxf(r2, r3)), 0.f);
    }
    lds[row][px][ci] = f2bf(v);
  }
  __syncthreads();
  f32x4 acc[4];
  #pragma unroll
  for (int c = 0; c < 4; ++c) acc[c] = (f32x4){0.f, 0.f, 0.f, 0.f};
  #pragma unroll
  for (int tap = 0; tap < 9; ++tap) {
    int dy = tap / 3, dx = tap % 3;
    bf16x8 af = *reinterpret_cast<const bf16x8*>(&lds[yloc + dy][p0 + col + dx][kg * 8]);
    #pragma unroll
    for (int c = 0; c < 4; ++c) {
      bf16x8 bfr = *reinterpret_cast<const bf16x8*>(wt3 + ((size_t)tap * 64 + c * 16 + col) * 32 + kg * 8);
      acc[c] = __builtin_amdgcn_mfma_f32_16x16x32_bf16(af, bfr, acc[c], 0, 0, 0);
    }
  }
  int yy = y0 + yloc, px = p0 + kg * 4;
  #pragma unroll
  for (int c = 0; c < 4; ++c) {
    ushort4 o;
    o.x = f2bf(acc[c][0]); o.y = f2bf(acc[c][1]); o.z = f2bf(acc[c][2]); o.w = f2bf(acc[c][3]);
    *reinterpret_cast<ushort4*>(outp + ((size_t)(b * 64 + c * 16 + col) * 32 + yy) * 32 + px) = o;
  }
}

// ---------------- conv4 via MFMA: CIN=64, COUT=64, HW=16; BN3+ReLU+maxpool fused at staging ----------------
__global__ __launch_bounds__(128)
void k_conv4_mfma(const unsigned short* __restrict__ in, const unsigned short* __restrict__ wt4,
                  const float* __restrict__ bnpart, const float* __restrict__ bng,
                  const float* __restrict__ bnb, unsigned short* __restrict__ outp) {
  const int b = blockIdx.x, y0 = blockIdx.y * 2;
  const int tid = threadIdx.x;
  const int w = tid >> 6, lane = tid & 63;
  const int col = lane & 15, kg = lane >> 4;
  __shared__ unsigned short lds[4][18][72];
  __shared__ float2 ssl[64];
  bn_ssl(ssl, bnpart, bng, bnb, 64, 16, 1.f / (float)(B_ * 1024));
  __syncthreads();
  for (int i = tid; i < 4 * 18 * 64; i += 128) {
    int px = i % 18, row = (i / 18) % 4, ci = i / 72;
    int gy = y0 + row - 1, gx = px - 1;
    float v = 0.f;
    if (gy >= 0 && gy < 16 && gx >= 0 && gx < 16) {
      float2 s = ssl[ci];
      size_t base = ((size_t)(b * 64 + ci) * 32 + 2 * gy) * 32 + 2 * gx;
      float r0 = fmaf(bf2f(in[base]),      s.x, s.y);
      float r1 = fmaf(bf2f(in[base + 1]),  s.x, s.y);
      float r2 = fmaf(bf2f(in[base + 32]), s.x, s.y);
      float r3 = fmaf(bf2f(in[base + 33]), s.x, s.y);
      v = fmaxf(fmaxf(fmaxf(r0, r1), fmaxf(r2, r3)), 0.f);
    }
    lds[row][px][ci] = f2bf(v);
  }
  __syncthreads();
  f32x4 acc[4];
  #pragma unroll
  for (int c = 0; c < 4; ++c) acc[c] = (f32x4){0.f, 0.f, 0.f, 0.f};
  #pragma unroll
  for (int tap = 0; tap < 9; ++tap) {
    int dy = tap / 3, dx = tap % 3;
    #pragma unroll
    for (int kc = 0; kc < 2; ++kc) {
      bf16x8 af = *reinterpret_cast<const bf16x8*>(&lds[w + dy][col + dx][kc * 32 + kg * 8]);
      #pragma unroll
      for (int c = 0; c < 4; ++c) {
        bf16x8 bfr = *reinterpret_cast<const bf16x8*>(wt4 + ((size_t)tap * 64 + c * 16 + col) * 64 + kc * 32 + kg * 8);
        acc[c] = __builtin_amdgcn_mfma_f32_16x16x32_bf16(af, bfr, acc[c], 0, 0, 0);
      }
    }
  }
  int yy = y0 + w, px = kg * 4;
  #pragma unroll
  for (int c = 0; c < 4; ++c) {
    ushort4 o;
    o.x = f2bf(acc[c][0]); o.y = f2bf(acc[c][1]); o.z = f2bf(acc[c][2]); o.w = f2bf(acc[c][3]);
    *reinterpret_cast<ushort4*>(outp + ((size_t)(b * 64 + c * 16 + col) * 16 + yy) * 16 + px) = o;
  }
}

// ---------------- BatchNorm stats on bf16 tensor (paired loads) ----------------
template<int C, int HW2>
__global__ __launch_bounds__(256)
void k_bn_stats_bf(const unsigned short* __restrict__ x, float* __restrict__ part) {
  int c = blockIdx.x, s = blockIdx.y, ns = gridDim.y;
  const int Np2 = B_ * HW2 / 2;
  float s1 = 0.f, s2 = 0.f;
  for (int ii = s * 256 + threadIdx.x; ii < Np2; ii += ns * 256) {
    int b = ii / (HW2 / 2), p2 = ii % (HW2 / 2);
    const unsigned short* pp = x + ((size_t)b * C + c) * HW2 + p2 * 2;
    unsigned u = *reinterpret_cast<const unsigned*>(pp);
    float v0 = __uint_as_float(u << 16);
    float v1 = __uint_as_float(u & 0xFFFF0000u);
    s1 += v0 + v1; s2 += v0 * v0 + v1 * v1;
  }
  __shared__ float r1[256], r2[256];
  r1[threadIdx.x] = s1; r2[threadIdx.x] = s2; __syncthreads();
  for (int off = 128; off > 0; off >>= 1) {
    if (threadIdx.x < off) { r1[threadIdx.x] += r1[threadIdx.x + off]; r2[threadIdx.x] += r2[threadIdx.x + off]; }
    __syncthreads();
  }
  if (threadIdx.x == 0) {
    part[(c * ns + s) * 2 + 0] = r1[0];
    part[(c * ns + s) * 2 + 1] = r2[0];
  }
}

// ---------------- bn4(folded) + relu + avg pool from bf16 ----------------
__global__ __launch_bounds__(256)
void k_avgpool_bn_bf(const unsigned short* __restrict__ x, const float* __restrict__ bnpart,
                     const float* __restrict__ g, const float* __restrict__ bb,
                     float* __restrict__ outp) {
  __shared__ float2 ssl[64];
  bn_ssl(ssl, bnpart, g, bb, 64, 8, 1.f / (float)(B_ * 256));
  __syncthreads();
  int idx = blockIdx.x * 256 + threadIdx.x;
  int b = idx >> 8;
  int r = idx & 255;
  int c = r >> 2, i = (r >> 1) & 1, j = r & 1;
  float2 s = ssl[c];
  const unsigned short* p = x + ((size_t)(b * 64 + c) * 16 + i * 8) * 16 + j * 8;
  float sum = 0.f;
  #pragma unroll
  for (int yy = 0; yy < 8; ++yy)
    #pragma unroll
    for (int xx = 0; xx < 8; ++xx)
      sum += fmaxf(fmaf(bf2f(p[yy * 16 + xx]), s.x, s.y), 0.f);
  outp[idx] = sum * (1.f / 64.f);
}

// ---------------- split-K GEMM: A(64 x K) @ W(K x NOUT) -> partials (fp32, encoder) ----------------
template<int K, int NOUT>
__global__ __launch_bounds__(256)
void k_gemm_part(const float* __restrict__ A, const float* __restrict__ W, int ldw,
                 float* __restrict__ part) {
  int jt = blockIdx.x, ks = blockIdx.y;
  int k0 = ks * 64;
  __shared__ float As[64][65];
  for (int i = threadIdx.x; i < 4096; i += 256) {
    int r = i >> 6, c = i & 63;
    As[r][c] = A[(size_t)r * K + k0 + c];
  }
  __syncthreads();
  int jsub = threadIdx.x & 31;
  int bg = threadIdx.x >> 5;
  int j = jt * 32 + jsub;
  float acc[8] = {0.f, 0.f, 0.f, 0.f, 0.f, 0.f, 0.f, 0.f};
  const float* wp = W + (size_t)k0 * ldw + j;
  #pragma unroll 8
  for (int kk = 0; kk < 64; ++kk) {
    float w = wp[(size_t)kk * ldw];
    #pragma unroll
    for (int r = 0; r < 8; ++r) acc[r] = fmaf(As[bg * 8 + r][kk], w, acc[r]);
  }
  float* pp = part + (size_t)ks * 64 * NOUT + j;
  #pragma unroll
  for (int r = 0; r < 8; ++r) pp[(size_t)(bg * 8 + r) * NOUT] = acc[r];
}

// ---------------- reduce partials + bias (+GLU) (+LN) ----------------
template<int NOUT, int NO_FIN, int KS, bool GLU_, bool LN_>
__global__ __launch_bounds__(256)
void k_fc_reduce(const float* __restrict__ part, const float* __restrict__ bias, int bstride,
                 const float* __restrict__ lng, const float* __restrict__ lnb,
                 float* __restrict__ outp) {
  constexpr int R = (NO_FIN + 255) / 256;
  int b = blockIdx.x, t = threadIdx.x;
  const float* bp = bias + (size_t)b * bstride;
  float v[R];
  #pragma unroll
  for (int r = 0; r < R; ++r) {
    int j = t + r * 256;
    if (j < NO_FIN) {
      float za = bp[j];
      float zb = GLU_ ? bp[j + NO_FIN] : 0.f;
      #pragma unroll
      for (int ks = 0; ks < KS; ++ks) {
        const float* pr = part + ((size_t)ks * 64 + b) * NOUT;
        za += pr[j];
        if (GLU_) zb += pr[j + NO_FIN];
      }
      v[r] = GLU_ ? za * sigmoidf_(zb) : za;
    } else v[r] = 0.f;
  }
  if (LN_) {
    __shared__ float red[256];
    float s1 = 0.f, s2 = 0.f;
    #pragma unroll
    for (int r = 0; r < R; ++r) { s1 += v[r]; s2 += v[r] * v[r]; }
    s1 = blockReduceSum(s1, red);
    s2 = blockReduceSum(s2, red);
    float mu = s1 / (float)NO_FIN;
    float rstd = rsqrtf(s2 / (float)NO_FIN - mu * mu + 1e-5f);
    #pragma unroll
    for (int r = 0; r < R; ++r) {
      int j = t + r * 256;
      if (j < NO_FIN) outp[(size_t)b * NO_FIN + j] = fmaf((v[r] - mu) * rstd, lng[j], lnb[j]);
    }
  } else {
    #pragma unroll
    for (int r = 0; r < R; ++r) {
      int j = t + r * 256;
      if (j < NO_FIN) outp[(size_t)b * NO_FIN + j] = v[r];
    }
  }
}

// ---------------- per-tick syn GEMM via MFMA ----------------
__global__ __launch_bounds__(256)
void k_syn_mfma(const unsigned short* __restrict__ Abf, const unsigned short* __restrict__ Bt,
                float* __restrict__ part) {
  const int jt = blockIdx.x, ks = blockIdx.y;
  const int w = threadIdx.x >> 6, lane = threadIdx.x & 63;
  const int col = lane & 15, kg = lane >> 4;
  const int jcol = jt * 64 + w * 16 + col;
  const int k0 = ks * 256;
  f32x4 acc[4];
  #pragma unroll
  for (int mt = 0; mt < 4; ++mt) acc[mt] = (f32x4){0.f, 0.f, 0.f, 0.f};
  #pragma unroll
  for (int kb = 0; kb < 8; ++kb) {
    const int kk = k0 + kb * 32 + kg * 8;
    bf16x8 bfr = *reinterpret_cast<const bf16x8*>(Bt + (size_t)jcol * 1024 + kk);
    #pragma unroll
    for (int mt = 0; mt < 4; ++mt) {
      bf16x8 a = *reinterpret_cast<const bf16x8*>(Abf + (size_t)(mt * 16 + col) * 1024 + kk);
      acc[mt] = __builtin_amdgcn_mfma_f32_16x16x32_bf16(a, bfr, acc[mt], 0, 0, 0);
    }
  }
  #pragma unroll
  for (int mt = 0; mt < 4; ++mt) {
    int b0 = mt * 16 + kg * 4;
    #pragma unroll
    for (int r = 0; r < 4; ++r)
      part[((size_t)ks * 64 + b0 + r) * 2048 + jcol] = acc[mt][r];
  }
}

// ---------------- per-tick: syn reduce = partials + syncst -> GLU -> LN -> trace(bf16,[n][b][m]) ----------------
__global__ __launch_bounds__(1024)
void k_syn_reduce(const float* __restrict__ part, const float* __restrict__ syncst,
                  const float* __restrict__ g, const float* __restrict__ bb,
                  unsigned short* __restrict__ trace, int slot) {
  int b = blockIdx.x, t = threadIdx.x;
  __shared__ float red[16];
  float za = syncst[b * 2048 + t];
  float zb = syncst[b * 2048 + 1024 + t];
  #pragma unroll
  for (int ks = 0; ks < 4; ++ks) {
    const float* pr = part + ((size_t)ks * 64 + b) * 2048;
    za += pr[t];
    zb += pr[t + 1024];
  }
  float v = za * sigmoidf_(zb);
  float s1 = bsum<16>(v, red);
  float s2 = bsum<16>(v * v, red);
  float mu = s1 * (1.f / 1024.f);
  float rstd = rsqrtf(s2 * (1.f / 1024.f) - mu * mu + 1e-5f);
  trace[((size_t)t * 64 + b) * 32 + slot] = f2bf(fmaf((v - mu) * rstd, g[t], bb[t]));
}

// ---------------- recurrent state init ----------------
__global__ __launch_bounds__(256)
void k_init(const float* __restrict__ sa, const float* __restrict__ st,
            const int* __restrict__ oL, const int* __restrict__ oR,
            float* __restrict__ act, unsigned short* __restrict__ act_bf,
            unsigned short* __restrict__ trace,
            float* __restrict__ ao, float* __restrict__ bo) {
  int idx = blockIdx.x * 256 + threadIdx.x;
  if (idx < B_ * N_ * M_) {
    int n = idx >> 11, m = idx & 31;
    trace[idx] = f2bf(st[n * 32 + m]);
  }
  if (idx < B_ * N_) {
    float v = sa[idx % N_];
    act[idx] = v;
    act_bf[idx] = f2bf(v);
  }
  if (idx < B_ * NSO_) {
    int i = idx % NSO_;
    ao[idx] = sa[oL[i]] * sa[oR[i]];
    bo[idx] = 1.f;
  }
}

// ---------------- per-tick: per-neuron private MLP via MFMA ----------------
__global__ __launch_bounds__(128)
void k_nlm_mfma(const unsigned short* __restrict__ trace, const unsigned short* __restrict__ w1t,
                const float* __restrict__ b1, const float* __restrict__ w2,
                const float* __restrict__ b2, float* __restrict__ act,
                unsigned short* __restrict__ act_bf, int tick) {
  const int w = threadIdx.x >> 6, lane = threadIdx.x & 63;
  const int n = blockIdx.x * 2 + w;
  const int col = lane & 15, kg = lane >> 4;
  __shared__ __align__(16) unsigned short ldsA[2][64][40];
  {
    const uint4* src = reinterpret_cast<const uint4*>(trace + ((size_t)n * 64 + lane) * 32);
    uint4 r0 = src[0], r1 = src[1], r2 = src[2], r3 = src[3];
    uint4* d = reinterpret_cast<uint4*>(&ldsA[w][lane][0]);
    d[0] = r0; d[1] = r1; d[2] = r2; d[3] = r3;
  }
  bf16x8 bf[16];
  float b1v[16], w2v[8];
  #pragma unroll
  for (int nt = 0; nt < 16; ++nt) {
    bf[nt] = *reinterpret_cast<const bf16x8*>(w1t + (((size_t)n * 256 + nt * 16 + col) * 32 + kg * 8));
    b1v[nt] = b1[n * 256 + nt * 16 + col];
  }
  #pragma unroll
  for (int nt = 0; nt < 8; ++nt) w2v[nt] = w2[n * 128 + nt * 16 + col];
  const float b2n = b2[n];
  const int kbase = kg * 8 + ((tick + 1) & 31);
  __syncthreads();
  #pragma unroll
  for (int mt = 0; mt < 4; ++mt) {
    const int brow = mt * 16 + col;
    bf16x8 af;
    #pragma unroll
    for (int j = 0; j < 8; ++j)
      af[j] = (short)ldsA[w][brow][(kbase + j) & 31];
    f32x4 acc[16];
    #pragma unroll
    for (int nt = 0; nt < 16; ++nt)
      acc[nt] = __builtin_amdgcn_mfma_f32_16x16x32_bf16(af, bf[nt], (f32x4){0.f, 0.f, 0.f, 0.f}, 0, 0, 0);
    float v0 = 0.f, v1 = 0.f, v2 = 0.f, v3 = 0.f;
    #pragma unroll
    for (int nt = 0; nt < 8; ++nt) {
      f32x4 za = acc[nt], zb = acc[nt + 8];
      float ba = b1v[nt], bg = b1v[nt + 8], wv = w2v[nt];
      v0 = fmaf((za[0] + ba) * sigmoidf_(zb[0] + bg), wv, v0);
      v1 = fmaf((za[1] + ba) * sigmoidf_(zb[1] + bg), wv, v1);
      v2 = fmaf((za[2] + ba) * sigmoidf_(zb[2] + bg), wv, v2);
      v3 = fmaf((za[3] + ba) * sigmoidf_(zb[3] + bg), wv, v3);
    }
    #pragma unroll
    for (int o = 1; o <= 8; o <<= 1) {
      v0 += __shfl_xor(v0, o); v1 += __shfl_xor(v1, o);
      v2 += __shfl_xor(v2, o); v3 += __shfl_xor(v3, o);
    }
    if (col == 0) {
      int b0 = mt * 16 + kg * 4;
      float r0 = v0 + b2n, r1 = v1 + b2n, r2 = v2 + b2n, r3 = v3 + b2n;
      act[(size_t)(b0 + 0) * 1024 + n] = r0;
      act[(size_t)(b0 + 1) * 1024 + n] = r1;
      act[(size_t)(b0 + 2) * 1024 + n] = r2;
      act[(size_t)(b0 + 3) * 1024 + n] = r3;
      act_bf[(size_t)(b0 + 0) * 1024 + n] = f2bf(r0);
      act_bf[(size_t)(b0 + 1) * 1024 + n] = f2bf(r1);
      act_bf[(size_t)(b0 + 2) * 1024 + n] = f2bf(r2);
      act_bf[(size_t)(b0 + 3) * 1024 + n] = f2bf(r3);
    }
  }
}

// ---------------- per-tick: sync_o + output MLP + pred + cert (1024 thr, split-K phases) ----------------
__global__ __launch_bounds__(1024)
void k_outpath(const float* __restrict__ act, float* __restrict__ ao, float* __restrict__ bo,
               const float* __restrict__ dec_o, const int* __restrict__ oL, const int* __restrict__ oR,
               const float* __restrict__ opw1, const float* __restrict__ opb1,
               const float* __restrict__ l1g, const float* __restrict__ l1b,
               const float* __restrict__ opw2, const float* __restrict__ opb2,
               const float* __restrict__ l2g, const float* __restrict__ l2b,
               const float* __restrict__ opw3, const float* __restrict__ opb3,
               float* __restrict__ outp, int tick) {
  int b = blockIdx.x, t = threadIdx.x;
  __shared__ float red[16];
  __shared__ float syo[256], h1s[256], h2s[64];
  __shared__ float zp1[4][256];
  __shared__ float zp2[16][64];
  const float* actb = act + (size_t)b * 1024;
  if (t < 256) {
    float po = actb[oL[t]] * actb[oR[t]];
    float r = __expf(-fminf(fmaxf(dec_o[t], 0.f), 15.f));
    int ai = b * 256 + t;
    float av = fmaf(r, ao[ai], po);
    float bv = fmaf(r, bo[ai], 1.f);
    ao[ai] = av; bo[ai] = bv;
    syo[t] = av * rsqrtf(bv + 1e-8f);
  }
  __syncthreads();
  {
    int j = t & 255, ks = t >> 8;
    float z = 0.f;
    const float* wcol = opw1 + j;
    #pragma unroll 8
    for (int k = ks * 64; k < ks * 64 + 64; ++k) z = fmaf(syo[k], wcol[k * 256], z);
    zp1[ks][j] = z;
  }
  __syncthreads();
  float h1v = 0.f;
  if (t < 256) h1v = zp1[0][t] + zp1[1][t] + zp1[2][t] + zp1[3][t] + opb1[t];
  float s1 = bsum<16>(t < 256 ? h1v : 0.f, red);
  float s2 = bsum<16>(t < 256 ? h1v * h1v : 0.f, red);
  if (t < 256) {
    float mu = s1 * (1.f / 256.f);
    float rstd = rsqrtf(s2 * (1.f / 256.f) - mu * mu + 1e-5f);
    h1s[t] = fmaxf(fmaf((h1v - mu) * rstd, l1g[t], l1b[t]), 0.f);
  }
  __syncthreads();
  {
    int j = t & 63, ks = t >> 6;
    float z = 0.f;
    const float* wcol = opw2 + j;
    #pragma unroll
    for (int k = ks * 16; k < ks * 16 + 16; ++k) z = fmaf(h1s[k], wcol[k * 64], z);
    zp2[ks][j] = z;
  }
  __syncthreads();
  if (t < 64) {
    float z2 = opb2[t];
    #pragma unroll
    for (int ks = 0; ks < 16; ++ks) z2 += zp2[ks][t];
    float a1 = z2, a2 = z2 * z2;
    #pragma unroll
    for (int o = 32; o > 0; o >>= 1) { a1 += __shfl_xor(a1, o); a2 += __shfl_xor(a2, o); }
    float mu2 = a1 * (1.f / 64.f);
    float rs2 = rsqrtf(a2 * (1.f / 64.f) - mu2 * mu2 + 1e-5f);
    h2s[t] = fmaxf(fmaf((z2 - mu2) * rs2, l2g[t], l2b[t]), 0.f);
  }
  __syncthreads();
  float z3 = 0.f;
  if (t < OUT_) {
    z3 = opb3[t];
    const float* wcol = opw3 + t;
    #pragma unroll 8
    for (int k = 0; k < 64; ++k) z3 = fmaf(h2s[k], wcol[k * OUT_], z3);
    outp[(size_t)b * (OUT_ * T_) + (size_t)t * T_ + tick] = z3;
  }
  float mx = bmax<16>(t < OUT_ ? z3 : -INFINITY, red);
  float e = (t < OUT_) ? __expf(z3 - mx) : 0.f;
  float S = bsum<16>(e, red);
  float inv = 1.f / S;
  float ep = 0.f;
  if (t < OUT_) {
    float p = e * inv;
    ep = p * __logf(p + 1e-10f);
  }
  float ent = -bsum<16>(ep, red);
  if (t == 0) {
    float ne = ent * (1.f / logf(1000.f));
    outp[(size_t)B_ * OUT_ * T_ + (size_t)b * 2 * T_ + tick]      = ne;
    outp[(size_t)B_ * OUT_ * T_ + (size_t)b * 2 * T_ + T_ + tick] = 1.f - ne;
  }
}

extern "C" void kernel_launch(void* const* d_in, const int* in_sizes, int n_in,
                              void* d_out, int out_size, void* d_ws, size_t ws_size,
                              hipStream_t stream) {
  (void)in_sizes; (void)n_in; (void)out_size; (void)ws_size;
  const float* x      = (const float*)d_in[0];
  const float* c1w    = (const float*)d_in[1];
  const float* bn1g   = (const float*)d_in[3];
  const float* bn1b   = (const float*)d_in[4];
  const float* c2w    = (const float*)d_in[5];
  const float* bn2g   = (const float*)d_in[7];
  const float* bn2b   = (const float*)d_in[8];
  const float* c3w    = (const float*)d_in[9];
  const float* bn3g   = (const float*)d_in[11];
  const float* bn3b   = (const float*)d_in[12];
  const float* c4w    = (const float*)d_in[13];
  const float* bn4g   = (const float*)d_in[15];
  const float* bn4b   = (const float*)d_in[16];
  const float* fc1w   = (const float*)d_in[17];
  const float* fc1b   = (const float*)d_in[18];
  const float* fc2w   = (const float*)d_in[19];
  const float* fc2b   = (const float*)d_in[20];
  const float* kvw    = (const float*)d_in[21];
  const float* kvb    = (const float*)d_in[22];
  const float* kvlg   = (const float*)d_in[23];
  const float* kvlb   = (const float*)d_in[24];
  const float* synw   = (const float*)d_in[25];
  const float* synb   = (const float*)d_in[26];
  const float* synlg  = (const float*)d_in[27];
  const float* synlb  = (const float*)d_in[28];
  const float* nlmw1  = (const float*)d_in[29];
  const float* nlmb1  = (const float*)d_in[30];
  const float* nlmw2  = (const float*)d_in[31];
  const float* nlmb2  = (const float*)d_in[32];
  const float* sact   = (const float*)d_in[33];
  const float* strc   = (const float*)d_in[34];
  const float* dec_o  = (const float*)d_in[36];
  const float* attn_inw = (const float*)d_in[39];
  const float* attn_inb = (const float*)d_in[40];
  const float* attn_ow  = (const float*)d_in[41];
  const float* attn_ob  = (const float*)d_in[42];
  const float* opw1   = (const float*)d_in[43];
  const float* opb1   = (const float*)d_in[44];
  const float* opl1g  = (const float*)d_in[45];
  const float* opl1b  = (const float*)d_in[46];
  const float* opw2   = (const float*)d_in[47];
  const float* opb2   = (const float*)d_in[48];
  const float* opl2g  = (const float*)d_in[49];
  const float* opl2b  = (const float*)d_in[50];
  const float* opw3   = (const float*)d_in[51];
  const float* opb3   = (const float*)d_in[52];
  const int*   oL     = (const int*)d_in[55];
  const int*   oR     = (const int*)d_in[56];
  float* outp = (float*)d_out;
  float* ws   = (float*)d_ws;

  // workspace (float offsets), R15/R17/R22 layout (measured 526.5 us).
  unsigned short* c1raw_bf = (unsigned short*)(ws + 8388608);
  unsigned short* c2raw_bf = (unsigned short*)ws;
  unsigned short* c3raw_bf = (unsigned short*)(ws + 8388608);
  unsigned short* c4raw_bf = (unsigned short*)ws;
  float* part  = ws + 4194304;
  unsigned short* trace_bf = (unsigned short*)(ws + 6291456);
  float* act   = ws + 8388608;
  float* syncst= ws + 8454144;
  float* pooled= ws + 8585216;
  float* ench  = ws + 8601600;
  float* enc   = ws + 8609792;
  float* kvbuf = ws + 8642560;
  float* vhbuf = ws + 8675328;
  float* aout  = ws + 8708096;
  float* ao    = ws + 8740864;
  float* bo    = ws + 8757248;
  unsigned short* w1t_bf   = (unsigned short*)(ws + 8777728);
  unsigned short* synw2t_bf= (unsigned short*)(ws + 12972032);
  unsigned short* wt2 = (unsigned short*)(ws + 14061568);
  unsigned short* wt3 = (unsigned short*)(ws + 14064128);
  unsigned short* wt4 = (unsigned short*)(ws + 14073344);
  float* bnpart = ws + 14091776;
  unsigned short* act_bf = (unsigned short*)(ws + 14095872);

  // ---- conv weights -> bf16 tap-major ----
  k_wprep<<<236,256,0,stream>>>(c2w, c3w, c4w, wt2, wt3, wt4);

  // ---- encoder convs (BN finalize + apply + pool fused into staging; MFMA compute) ----
  k_conv1<<<dim3(64,16),256,0,stream>>>(x, c1w, c1raw_bf);
  k_bn_stats_bf<16,4096><<<dim3(16,32),256,0,stream>>>(c1raw_bf, bnpart);

  k_conv2_mfma<<<dim3(64,64),256,0,stream>>>(c1raw_bf, wt2, bnpart, bn1g, bn1b, c2raw_bf);
  k_bn_stats_bf<32,4096><<<dim3(32,32),256,0,stream>>>(c2raw_bf, bnpart);

  k_conv3_mfma<<<dim3(64,16),256,0,stream>>>(c2raw_bf, wt3, bnpart, bn2g, bn2b, c3raw_bf);
  k_bn_stats_bf<64,1024><<<dim3(64,16),256,0,stream>>>(c3raw_bf, bnpart);

  k_conv4_mfma<<<dim3(64,8),128,0,stream>>>(c3raw_bf, wt4, bnpart, bn3g, bn3b, c4raw_bf);

  k_w1t<<<1024,256,0,stream>>>(nlmw1, w1t_bf);
  k_synwt<<<dim3(32,16),256,0,stream>>>(synw + (size_t)512 * 2048, synw2t_bf);

  k_bn_stats_bf<64,256><<<dim3(64,8),256,0,stream>>>(c4raw_bf, bnpart);
  k_avgpool_bn_bf<<<64,256,0,stream>>>(c4raw_bf, bnpart, bn4g, bn4b, pooled);

  // ---- encoder FC chain (split-K GEMM + fused reduce; many-block structure) ----
  k_gemm_part<256,256><<<dim3(8,4),256,0,stream>>>(pooled, fc1w, 256, part);
  k_fc_reduce<256,128,4,true,false><<<64,256,0,stream>>>(part, fc1b, 0, nullptr, nullptr, ench);
  k_gemm_part<128,512><<<dim3(16,2),256,0,stream>>>(ench, fc2w, 512, part);
  k_fc_reduce<512,512,2,false,false><<<64,256,0,stream>>>(part, fc2b, 0, nullptr, nullptr, enc);
  k_gemm_part<512,512><<<dim3(16,8),256,0,stream>>>(enc, kvw, 512, part);
  k_fc_reduce<512,512,8,false,true><<<64,256,0,stream>>>(part, kvb, 0, kvlg, kvlb, kvbuf);
  // vh = kv @ Wv + bv (attention softmax over single key == 1 -> q,k branches dead)
  k_gemm_part<512,512><<<dim3(16,8),256,0,stream>>>(kvbuf, attn_inw + 1024, 1536, part);
  k_fc_reduce<512,512,8,false,false><<<64,256,0,stream>>>(part, attn_inb + 1024, 0, nullptr, nullptr, vhbuf);
  k_gemm_part<512,512><<<dim3(16,8),256,0,stream>>>(vhbuf, attn_ow, 512, part);
  k_fc_reduce<512,512,8,false,false><<<64,256,0,stream>>>(part, attn_ob, 0, nullptr, nullptr, aout);
  k_gemm_part<512,2048><<<dim3(64,8),256,0,stream>>>(aout, synw, 2048, part);
  k_fc_reduce<2048,2048,8,false,false><<<64,256,0,stream>>>(part, synb, 0, nullptr, nullptr, syncst);

  k_init<<<8192,256,0,stream>>>(sact, strc, oL, oR, act, act_bf, trace_bf, ao, bo);

  // ---- recurrent ticks ----
  for (int t = 0; t < T_; ++t) {
    k_syn_mfma<<<dim3(32,4),256,0,stream>>>(act_bf, synw2t_bf, part);
    k_syn_reduce<<<64,1024,0,stream>>>(part, syncst, synlg, synlb, trace_bf, t);
    k_nlm_mfma<<<512,128,0,stream>>>(trace_bf, w1t_bf, nlmb1, nlmw2, nlmb2, act, act_bf, t);
    k_outpath<<<64,1024,0,stream>>>(act, ao, bo, dec_o, oL, oR,
                                    opw1, opb1, opl1g, opl1b,
                                    opw2, opb2, opl2g, opl2b,
                                    opw3, opb3, outp, t);
  }
}